// Round 2
// baseline (736.382 us; speedup 1.0000x reference)
//
#include <hip/hip_runtime.h>
#include <hip/hip_bf16.h>

#define SEQ_LEN 4096
#define D_MODEL 512
#define KSZ 33

typedef __attribute__((ext_vector_type(8))) short short8;
typedef __attribute__((ext_vector_type(4))) short short4v;
typedef __attribute__((ext_vector_type(4))) float float4v;
typedef __attribute__((ext_vector_type(4))) unsigned short ushort4v;

static __device__ __forceinline__ unsigned short f2bf(float f) {
    unsigned int u = __float_as_uint(f);
    u += 0x7fffu + ((u >> 16) & 1u);   // round-to-nearest-even
    return (unsigned short)(u >> 16);
}

// ---------------- K1: residual depthwise conv, fp32 -> fp32 (into d_out) ---
// grid (64 l-tiles, 8 d-tiles, 32 b); block 256.
__global__ __launch_bounds__(256) void k_conv(const float* __restrict__ h,
                                              const float* __restrict__ cw,
                                              float* __restrict__ hagg) {
    __shared__ float tile[96][64];   // rows l0-16 .. l0+79
    __shared__ float wsh[64][33];

    const int lt = blockIdx.x, dt = blockIdx.y, b = blockIdx.z;
    const int tid = threadIdx.x;
    const int c = tid & 63;          // local d
    const int l0 = lt * 64;

    const float* hb = h + ((size_t)b * SEQ_LEN) * D_MODEL + dt * 64;
    for (int r = (tid >> 6); r < 96; r += 4) {
        int l = l0 - 16 + r;
        float v = 0.f;
        if (l >= 0 && l < SEQ_LEN) v = hb[(size_t)l * D_MODEL + c];
        tile[r][c] = v;
    }
    for (int idx = tid; idx < 64 * KSZ; idx += 256) {
        int dd = idx / KSZ, k = idx - dd * KSZ;
        wsh[dd][k] = cw[(size_t)(dt * 64 + dd) * KSZ + k];
    }
    __syncthreads();

    float wreg[KSZ];
#pragma unroll
    for (int k = 0; k < KSZ; k++) wreg[k] = wsh[c][k];

    const int lsub = (tid >> 6) * 16;
    float win[48];
#pragma unroll
    for (int t = 0; t < 48; t++) win[t] = tile[lsub + t][c];

    float acc[16];
#pragma unroll
    for (int j = 0; j < 16; j++) acc[j] = win[j + 16];   // residual (h itself)
#pragma unroll
    for (int k = 0; k < KSZ; k++)
#pragma unroll
        for (int j = 0; j < 16; j++)
            acc[j] += wreg[k] * win[j + k];

    float* ob = hagg + ((size_t)b * SEQ_LEN + l0 + lsub) * D_MODEL + dt * 64 + c;
#pragma unroll
    for (int j = 0; j < 16; j++) ob[(size_t)j * D_MODEL] = acc[j];
}

// ---------------- K2: per-phase GEMM on MFMA, IN-PLACE on d_out ------------
// grid (8 d-tiles, 32 phases, 32 b); block 256 = 4 waves.
// Block (dtile,ph,b) reads X = out[(b*4096 + i*32+ph)*512 + dtile*64 + d]
// (i,d in [0,128)x[0,64)) and writes Y to the exact same element set
// (hidx = m*32+ph). Unique-owner per region; reads precede writes within
// the block (staging completes before __syncthreads; epilogue after).
#define WS 136   // W_lds row stride (bf16)
#define XS 132   // X_lds row stride (bf16)

__global__ __launch_bounds__(256) void k_gemm(const float* __restrict__ w,
                                              float* __restrict__ out) {
    __shared__ unsigned short wl[128 * WS];   // 34816 B
    __shared__ unsigned short xl[64 * XS];    // 16896 B

    const int tid = threadIdx.x;
    const int dtile = blockIdx.x, ph = blockIdx.y, b = blockIdx.z;

    // --- stage W: fp32 [m][i] -> bf16 row-major in LDS ---
#pragma unroll
    for (int it = 0; it < 16; it++) {
        int idx = it * 1024 + tid * 4;
        int row = idx >> 7, col = idx & 127;
        float4v v = *(const float4v*)(w + idx);
        ushort4v o;
        o[0] = f2bf(v[0]); o[1] = f2bf(v[1]); o[2] = f2bf(v[2]); o[3] = f2bf(v[3]);
        *(ushort4v*)(&wl[row * WS + col]) = o;
    }
    // --- stage X transposed: xl[d][i], fp32 -> bf16 ---
    {
        const int dgrp = tid & 15;       // d = 4*dgrp .. +3
        const int ipair = tid >> 4;      // i pairs
        const float* xb = out + ((size_t)b * SEQ_LEN + ph) * D_MODEL
                          + dtile * 64 + dgrp * 4;
#pragma unroll
        for (int pass = 0; pass < 4; pass++) {
            int i0 = pass * 32 + ipair * 2;
            float4v v0 = *(const float4v*)(xb + (size_t)(i0) * 32 * D_MODEL);
            float4v v1 = *(const float4v*)(xb + (size_t)(i0 + 1) * 32 * D_MODEL);
#pragma unroll
            for (int dd = 0; dd < 4; dd++) {
                unsigned int pk = (unsigned int)f2bf(v0[dd])
                                | ((unsigned int)f2bf(v1[dd]) << 16);
                *(unsigned int*)(&xl[(dgrp * 4 + dd) * XS + i0]) = pk;
            }
        }
    }
    __syncthreads();

    const int lane = tid & 63, wid = tid >> 6;
    const int q = lane >> 4, r16 = lane & 15;

    float4v acc[2][4] = {};
#pragma unroll
    for (int kb = 0; kb < 128; kb += 32) {
        short8 a[2];
#pragma unroll
        for (int mt = 0; mt < 2; mt++) {
            int row = wid * 32 + mt * 16 + r16;             // m
            a[mt] = *(const short8*)(&wl[row * WS + kb + q * 8]);
        }
#pragma unroll
        for (int dtl = 0; dtl < 4; dtl++) {
            const unsigned short* xp = &xl[(dtl * 16 + r16) * XS + kb + q * 8];
            short4v blo = *(const short4v*)(xp);
            short4v bhi = *(const short4v*)(xp + 4);
            short8 bfrag = __builtin_shufflevector(blo, bhi, 0, 1, 2, 3, 4, 5, 6, 7);
#pragma unroll
            for (int mt = 0; mt < 2; mt++)
                acc[mt][dtl] = __builtin_amdgcn_mfma_f32_16x16x32_bf16(
                    a[mt], bfrag, acc[mt][dtl], 0, 0, 0);
        }
    }

    // --- epilogue: D col = lane&15 -> d, row = quad*4 + reg -> m ---
    float* ob = out + ((size_t)b * SEQ_LEN) * D_MODEL;
#pragma unroll
    for (int mt = 0; mt < 2; mt++) {
        int mbase = wid * 32 + mt * 16 + q * 4;
#pragma unroll
        for (int r = 0; r < 4; r++) {
            int m = mbase + r;
            int hidx = m * 32 + ph;
#pragma unroll
            for (int dtl = 0; dtl < 4; dtl++) {
                int d = dtile * 64 + dtl * 16 + r16;
                ob[(size_t)hidx * D_MODEL + d] = acc[mt][dtl][r];
            }
        }
    }
}

extern "C" void kernel_launch(void* const* d_in, const int* in_sizes, int n_in,
                              void* d_out, int out_size, void* d_ws, size_t ws_size,
                              hipStream_t stream) {
    const float* h  = (const float*)d_in[0];
    const float* cw = (const float*)d_in[1];   // [512][1][33]
    const float* bw = (const float*)d_in[2];   // [128][128]
    float* out = (float*)d_out;

    k_conv<<<dim3(64, 8, 32), 256, 0, stream>>>(h, cw, out);
    k_gemm<<<dim3(8, 32, 32), 256, 0, stream>>>(bw, out);
}